// Round 1
// 215.261 us; speedup vs baseline: 1.0144x; 1.0144x over previous
//
#include <hip/hip_runtime.h>
#include <stdint.h>
#include <math.h>

// BSRBF-KAN layer, FUSED: out = relu(LN(x)) @ base_W^T + (bspline+rbf)(LN(x)) @ spline_W^T
// K = 512 (relu region, staged from precomputed A0 via global_load_lds)
//   + 4096 (basis region, COMPUTED per K-tile directly into swizzled LDS slots).
// This removes the 151 MB A-matrix write + 300 MB re-read and overlaps the
// basis VALU with MFMA (gemm was MfmaUtil 35% / VALUBusy 13% -> idle VALU pipe).
// Tile: BM=128 x BN=256, BK=64, 8 waves (wm=wave&1, wn=wave>>1), 48 KB LDS,
// grid=256 (1 block/CU, 2 waves/SIMD). Basis recompute replication = N/BN = 2x.
//   ws: [W: 512*4608 bf16][XN: 16384*512 fp16][A0: 16384*512 bf16]

#define D_IN  512
#define D_OUT 512
#define NB    8
#define KTOT  (D_IN + D_IN * NB)   // 4608
#define ROWS  16384

typedef __attribute__((ext_vector_type(8))) short short8;
typedef __attribute__((ext_vector_type(4))) float f32x4;

__device__ __forceinline__ unsigned f2bfu(float f) {
  union { float f; unsigned u; } v; v.f = f;
  return (v.u + 0x7fffu + ((v.u >> 16) & 1u)) >> 16;  // RNE, finite inputs
}
__device__ __forceinline__ short f2bf(float f) { return (short)f2bfu(f); }
__device__ __forceinline__ float h2f(unsigned short u) {
  return (float)__builtin_bit_cast(_Float16, u);
}

// ---------------- weight prep: interleave + fp32->bf16 -------------------
__global__ __launch_bounds__(256) void wprep_kernel(
    const float* __restrict__ bw, const float* __restrict__ sw,
    short* __restrict__ W) {
  const int o = blockIdx.x;
  for (int k = threadIdx.x; k < KTOT; k += 256) {
    const float v = (k < D_IN) ? bw[o * D_IN + k]
                               : sw[(size_t)o * (D_IN * NB) + (k - D_IN)];
    W[(size_t)o * KTOT + k] = f2bf(v);
  }
}

// ---------------- LayerNorm: x -> xn (fp16) and relu(xn) (bf16) ----------
// one wave per row; lane owns d = lane*8 .. lane*8+7 (float4 loads, uint4 stores)
__global__ __launch_bounds__(256) void ln_kernel(
    const float* __restrict__ x, const float* __restrict__ gamma,
    const float* __restrict__ beta, short* __restrict__ XN,
    short* __restrict__ A0) {
  const int tid = threadIdx.x;
  const int lane = tid & 63, wave = tid >> 6;
  const int row = blockIdx.x * 4 + wave;
  const float* xr = x + (size_t)row * D_IN + lane * 8;

  const float4 a = *(const float4*)(xr);
  const float4 b = *(const float4*)(xr + 4);
  float xv[8] = {a.x, a.y, a.z, a.w, b.x, b.y, b.z, b.w};
  float s = 0.0f, ss = 0.0f;
#pragma unroll
  for (int e = 0; e < 8; e++) { s += xv[e]; ss += xv[e] * xv[e]; }
#pragma unroll
  for (int off = 32; off > 0; off >>= 1) {
    s += __shfl_xor(s, off);
    ss += __shfl_xor(ss, off);
  }
  const float mu = s * (1.0f / D_IN);
  const float var = ss * (1.0f / D_IN) - mu * mu;
  const float rstd = 1.0f / sqrtf(var + 1e-5f);

  const float4 g0 = *(const float4*)(gamma + lane * 8);
  const float4 g1 = *(const float4*)(gamma + lane * 8 + 4);
  const float4 b0 = *(const float4*)(beta + lane * 8);
  const float4 b1 = *(const float4*)(beta + lane * 8 + 4);
  float gv[8] = {g0.x, g0.y, g0.z, g0.w, g1.x, g1.y, g1.z, g1.w};
  float bv[8] = {b0.x, b0.y, b0.z, b0.w, b1.x, b1.y, b1.z, b1.w};

  unsigned xp[4], rp[4];
#pragma unroll
  for (int h = 0; h < 4; h++) {
    const float n0 = (xv[2 * h] - mu) * rstd * gv[2 * h] + bv[2 * h];
    const float n1 = (xv[2 * h + 1] - mu) * rstd * gv[2 * h + 1] + bv[2 * h + 1];
    const unsigned h0 = (unsigned)__builtin_bit_cast(unsigned short, (_Float16)n0);
    const unsigned h1 = (unsigned)__builtin_bit_cast(unsigned short, (_Float16)n1);
    xp[h] = h0 | (h1 << 16);
    rp[h] = f2bfu(fmaxf(n0, 0.0f)) | (f2bfu(fmaxf(n1, 0.0f)) << 16);
  }
  const uint4 xq = {xp[0], xp[1], xp[2], xp[3]};
  const uint4 rq = {rp[0], rp[1], rp[2], rp[3]};
  *(uint4*)&XN[(size_t)row * D_IN + lane * 8] = xq;
  *(uint4*)&A0[(size_t)row * D_IN + lane * 8] = rq;
}

// ---------------- basis eval: one d -> 8 packed bf16 (spline + rbf) ------
// closed-form uniform cubic B-spline, knots (i-3)*0.6 - 1.5.
// In-range clamp dropped: for c<0 or c>10, m=c-j never hits 0..3 for j in 0..7,
// so selection yields 0 automatically (exact vs reference).
// RBF: exp(-tt^2) = exp2(-(w - cj)^2), w = xn*(7/3)*sqrt(log2 e).
__device__ __forceinline__ void basis_store(float xn, short* dst) {
  const float u = xn * (1.0f / 0.6f) + 5.5f;
  const float cf = floorf(u);
  const int c = (int)cf;
  const float t = u - cf;
  const float t2 = t * t, t3 = t2 * t;
  const float omt = 1.0f - t;
  const float v0 = t3 * (1.0f / 6.0f);
  const float v1 = (1.0f / 6.0f) * (1.0f + 3.0f * t + 3.0f * t2 - 3.0f * t3);
  const float v2 = (1.0f / 6.0f) * (4.0f - 6.0f * t2 + 3.0f * t3);
  const float v3 = (1.0f / 6.0f) * omt * omt * omt;
  const float w = xn * 2.80261895e0f;  // (7/3)*sqrt(log2 e)

  unsigned pk[4];
#pragma unroll
  for (int h = 0; h < 4; h++) {
    float o0, o1;
#pragma unroll
    for (int sub = 0; sub < 2; sub++) {
      const int j = 2 * h + sub;
      const int m = c - j;
      float sp = 0.0f;
      sp = (m == 0) ? v0 : sp;
      sp = (m == 1) ? v1 : sp;
      sp = (m == 2) ? v2 : sp;
      sp = (m == 3) ? v3 : sp;
      const float cj = ((float)j - 3.5f) * 1.20112240878645e0f;  // folds to literal
      const float dj = w - cj;
      const float o = sp + __builtin_amdgcn_exp2f(-(dj * dj));
      if (sub == 0) o0 = o; else o1 = o;
    }
    asm("v_cvt_pk_bf16_f32 %0, %1, %2" : "=v"(pk[h]) : "v"(o0), "v"(o1));
  }
  const uint4 v4 = {pk[0], pk[1], pk[2], pk[3]};
  *(uint4*)dst = v4;  // ds_write_b128, conflict-free (contiguous 1KB/wave)
}

// ---------------- fused bf16 MFMA GEMM -----------------------------------
// LDS slot (r, c) holds global chunk c ^ (r & 7)  (XOR bank swizzle, 0 conflicts)
#define GLL(g, l)                                               \
  __builtin_amdgcn_global_load_lds(                             \
      (const __attribute__((address_space(1))) void*)(g),       \
      (__attribute__((address_space(3))) void*)(l), 16, 0, 0)

__global__ __launch_bounds__(512) void gemm_kernel(
    const short* __restrict__ A0, const short* __restrict__ XN,
    const short* __restrict__ W, float* __restrict__ out) {
  __shared__ short As[128 * 64];  // 16 KB
  __shared__ short Bs[256 * 64];  // 32 KB
  const int tid = threadIdx.x;
  const int lane = tid & 63, wave = tid >> 6;

  const int f = blockIdx.x;          // 256 blocks: pair 2g,2g+1 shares A m-tile
  const int m0 = (f >> 1) * 128;
  const int n0 = (f & 1) * 256;
  const int wm = wave & 1, wn = wave >> 1;  // per-wave 64x64 output

  const f32x4 zero = {0.0f, 0.0f, 0.0f, 0.0f};
  f32x4 acc[4][4];
#pragma unroll
  for (int i = 0; i < 4; i++)
#pragma unroll
    for (int j = 0; j < 4; j++) acc[i][j] = zero;

  // staging map: thread -> (row r0 = tid>>3 in 0..63, chunk-slot c0 = tid&7);
  // rounds add +64 rows. Source global chunk q0 = c0 ^ (r0 & 7).
  const int r0 = tid >> 3;
  const int c0 = tid & 7;
  const int q0 = c0 ^ (r0 & 7);
  const short* gA = A0 + (size_t)(m0 + r0) * D_IN + q0 * 8;
  const short* gB = W + (size_t)(n0 + r0) * KTOT + q0 * 8;
  const unsigned short* gX =
      (const unsigned short*)XN + (size_t)(m0 + r0) * D_IN + q0;
  short* lA = As + wave * 512;  // wave-uniform base; HW scatters lane*16B
  short* lB = Bs + wave * 512;

  const int lr = lane & 15;
  const int q = lane >> 4;
  const int x7 = lr & 7;

#define MFMA_STEP()                                                            \
  do {                                                                         \
    _Pragma("unroll")                                                          \
    for (int kk2 = 0; kk2 < 2; kk2++) {                                        \
      const int gq = kk2 * 4 + q;                                              \
      short8 af[4], bfv[4];                                                    \
      _Pragma("unroll")                                                        \
      for (int mi = 0; mi < 4; mi++)                                           \
        af[mi] = *(const short8*)&As[(wm * 64 + mi * 16 + lr) * 64 +           \
                                     ((gq ^ x7) * 8)];                         \
      _Pragma("unroll")                                                        \
      for (int nj = 0; nj < 4; nj++)                                           \
        bfv[nj] = *(const short8*)&Bs[(wn * 64 + nj * 16 + lr) * 64 +          \
                                      ((gq ^ x7) * 8)];                        \
      _Pragma("unroll")                                                        \
      for (int mi = 0; mi < 4; mi++)                                           \
        _Pragma("unroll")                                                      \
        for (int nj = 0; nj < 4; nj++)                                         \
          acc[mi][nj] = __builtin_amdgcn_mfma_f32_16x16x32_bf16(               \
              af[mi], bfv[nj], acc[mi][nj], 0, 0, 0);                          \
    }                                                                          \
  } while (0)

  // ---- relu region: kt in [0, 512), A0 staged via global_load_lds ----
  for (int kt = 0; kt < D_IN; kt += 64) {
    __syncthreads();
    GLL(gA + kt, lA);
    GLL(gA + (size_t)64 * D_IN + kt, lA + 4096);
#pragma unroll
    for (int rd = 0; rd < 4; rd++)
      GLL(gB + (size_t)(64 * rd) * KTOT + kt, lB + rd * 4096);
    __syncthreads();
    MFMA_STEP();
  }

  // ---- basis region: kt in [512, 4608), As computed in-register ----
  // thread's slot (r, c0) holds chunk q0 -> d = dof + q0, all 8 j's.
  unsigned short pa = gX[0];
  unsigned short pb = gX[(size_t)64 * D_IN];
  for (int kt = D_IN; kt < KTOT; kt += 64) {
    const int dof = (kt - D_IN) >> 3;
    const unsigned short ca = pa, cb = pb;
    if (kt + 64 < KTOT) {  // prefetch next tile's xn (1 K-tile of latency)
      pa = gX[dof + 8];
      pb = gX[(size_t)64 * D_IN + dof + 8];
    }
    __syncthreads();
#pragma unroll
    for (int rd = 0; rd < 4; rd++)
      GLL(gB + (size_t)(64 * rd) * KTOT + kt, lB + rd * 4096);
    basis_store(h2f(ca), &As[r0 * 64 + c0 * 8]);
    basis_store(h2f(cb), &As[(r0 + 64) * 64 + c0 * 8]);
    __syncthreads();
    MFMA_STEP();
  }

  // C/D layout (m89-verified): col = lane&15, row = (lane>>4)*4 + reg
#pragma unroll
  for (int mi = 0; mi < 4; mi++) {
#pragma unroll
    for (int nj = 0; nj < 4; nj++) {
      const int gcol = n0 + wn * 64 + nj * 16 + lr;
#pragma unroll
      for (int r = 0; r < 4; r++) {
        const int grow = m0 + wm * 64 + mi * 16 + q * 4 + r;
        out[(size_t)grow * D_OUT + gcol] = acc[mi][nj][r];
      }
    }
  }
#undef MFMA_STEP
}

extern "C" void kernel_launch(void* const* d_in, const int* in_sizes, int n_in,
                              void* d_out, int out_size, void* d_ws, size_t ws_size,
                              hipStream_t stream) {
  const float* x     = (const float*)d_in[0];
  const float* gamma = (const float*)d_in[1];
  const float* beta  = (const float*)d_in[2];
  const float* bw    = (const float*)d_in[3];
  const float* sw    = (const float*)d_in[4];
  float* out = (float*)d_out;

  short* W  = (short*)d_ws;                          // 512 * 4608 bf16
  short* XN = W + (size_t)D_OUT * KTOT;              // 16384 * 512 fp16
  short* A0 = XN + (size_t)ROWS * D_IN;              // 16384 * 512 bf16

  wprep_kernel<<<D_OUT, 256, 0, stream>>>(bw, sw, W);
  ln_kernel<<<ROWS / 4, 256, 0, stream>>>(x, gamma, beta, XN, A0);
  gemm_kernel<<<256, 512, 0, stream>>>(A0, XN, W, out);
}

// Round 2
// 202.048 us; speedup vs baseline: 1.0807x; 1.0654x over previous
//
#include <hip/hip_runtime.h>
#include <stdint.h>
#include <math.h>

// BSRBF-KAN layer, FUSED + PIPELINED:
// out = relu(LN(x)) @ base_W^T + (bspline+rbf)(LN(x)) @ spline_W^T
// K = 512 (relu region, A0 staged via global_load_lds)
//   + 4096 (basis region, computed per K-tile directly into LDS).
// Round-2 change: double-buffered As/Bs with ONE barrier per K-tile.
// Iteration t: frag-read tile t -> GLL B[t+1] -> basis-compute A[t+1]
// (other buffer) -> MFMA tile t -> barrier.  Basis VALU and MFMA are
// independent in the same region, so they interleave (round-1 had them in
// separate barrier phases: VALU 52% + MFMA 24% summed serially).
// Basis math: RBF via cascade from middle anchor (3 trans instead of 8):
//   R_j = exp2(-(z-j*d)^2), d^2 = log2(e)  =>  R_{j+1} = R_j * G * e^-(2j+1),
//   G = exp2(2dz).  Spline select: 11 shared compares (c==k) + cndmask chain.
// Tile: BM=128 x BN=256, BK=64, 8 waves, 96 KB LDS, grid=256 (1 block/CU).
// n-minor block order: XCD = f%8 sees a single W n-half (2.36 MB < 4 MB L2).
//   ws: [W: 512*4608 bf16][XN: 16384*512 fp16][A0: 16384*512 bf16]

#define D_IN  512
#define D_OUT 512
#define NB    8
#define KTOT  (D_IN + D_IN * NB)   // 4608
#define ROWS  16384

typedef __attribute__((ext_vector_type(8))) short short8;
typedef __attribute__((ext_vector_type(4))) float f32x4;

__device__ __forceinline__ unsigned f2bfu(float f) {
  union { float f; unsigned u; } v; v.f = f;
  return (v.u + 0x7fffu + ((v.u >> 16) & 1u)) >> 16;  // RNE, finite inputs
}
__device__ __forceinline__ short f2bf(float f) { return (short)f2bfu(f); }
__device__ __forceinline__ float h2f(unsigned short u) {
  return (float)__builtin_bit_cast(_Float16, u);
}

// ---------------- prep: weight interleave + LayerNorm, one launch --------
__global__ __launch_bounds__(256) void prep_kernel(
    const float* __restrict__ x, const float* __restrict__ gamma,
    const float* __restrict__ beta, const float* __restrict__ bw,
    const float* __restrict__ sw, short* __restrict__ XN,
    short* __restrict__ A0, short* __restrict__ W) {
  if (blockIdx.x >= ROWS / 4) {
    // ---- weight prep: interleave + fp32->bf16, one block per out-row ----
    const int o = blockIdx.x - ROWS / 4;
    for (int k = threadIdx.x; k < KTOT; k += 256) {
      const float v = (k < D_IN) ? bw[o * D_IN + k]
                                 : sw[(size_t)o * (D_IN * NB) + (k - D_IN)];
      W[(size_t)o * KTOT + k] = f2bf(v);
    }
    return;
  }
  // ---- LayerNorm: x -> xn (fp16) and relu(xn) (bf16); wave per row ----
  const int tid = threadIdx.x;
  const int lane = tid & 63, wave = tid >> 6;
  const int row = blockIdx.x * 4 + wave;
  const float* xr = x + (size_t)row * D_IN + lane * 8;

  const float4 a = *(const float4*)(xr);
  const float4 b = *(const float4*)(xr + 4);
  float xv[8] = {a.x, a.y, a.z, a.w, b.x, b.y, b.z, b.w};
  float s = 0.0f, ss = 0.0f;
#pragma unroll
  for (int e = 0; e < 8; e++) { s += xv[e]; ss += xv[e] * xv[e]; }
#pragma unroll
  for (int off = 32; off > 0; off >>= 1) {
    s += __shfl_xor(s, off);
    ss += __shfl_xor(ss, off);
  }
  const float mu = s * (1.0f / D_IN);
  const float var = ss * (1.0f / D_IN) - mu * mu;
  const float rstd = 1.0f / sqrtf(var + 1e-5f);

  const float4 g0 = *(const float4*)(gamma + lane * 8);
  const float4 g1 = *(const float4*)(gamma + lane * 8 + 4);
  const float4 b0 = *(const float4*)(beta + lane * 8);
  const float4 b1 = *(const float4*)(beta + lane * 8 + 4);
  float gv[8] = {g0.x, g0.y, g0.z, g0.w, g1.x, g1.y, g1.z, g1.w};
  float bv[8] = {b0.x, b0.y, b0.z, b0.w, b1.x, b1.y, b1.z, b1.w};

  unsigned xp[4], rp[4];
#pragma unroll
  for (int h = 0; h < 4; h++) {
    const float n0 = (xv[2 * h] - mu) * rstd * gv[2 * h] + bv[2 * h];
    const float n1 = (xv[2 * h + 1] - mu) * rstd * gv[2 * h + 1] + bv[2 * h + 1];
    const unsigned h0 = (unsigned)__builtin_bit_cast(unsigned short, (_Float16)n0);
    const unsigned h1 = (unsigned)__builtin_bit_cast(unsigned short, (_Float16)n1);
    xp[h] = h0 | (h1 << 16);
    rp[h] = f2bfu(fmaxf(n0, 0.0f)) | (f2bfu(fmaxf(n1, 0.0f)) << 16);
  }
  const uint4 xq = {xp[0], xp[1], xp[2], xp[3]};
  const uint4 rq = {rp[0], rp[1], rp[2], rp[3]};
  *(uint4*)&XN[(size_t)row * D_IN + lane * 8] = xq;
  *(uint4*)&A0[(size_t)row * D_IN + lane * 8] = rq;
}

// ---------------- basis eval: one d -> 8 packed bf16 (spline + rbf) ------
// Spline: closed-form uniform cubic B-spline, knots (i-3)*0.6 - 1.5.
// Out-of-range c needs no clamp: c==j+m never hits for c outside [0,10].
// RBF cascade: z = (xn+1.5)*(7/3)*sqrt(log2 e); R_j = exp2(-(z - j*DLT)^2),
// DLT = 1.20112241, DLT^2 = log2 e, so R_{j+1} = R_j * G * e^-(2j+1),
// G = exp2(2*DLT*z).  Anchor at j=3 (middle) so no material underflow.
__device__ __forceinline__ void basis_write(float xn, short* dst) {
  const float u = fmaf(xn, 1.66666667f, 5.5f);  // (xn+3.3)/0.6
  const float cf = floorf(u);
  const int c = (int)cf;
  const float t = u - cf;
  const float t2 = t * t, t3 = t2 * t;
  const float omt = 1.0f - t;
  const float v0 = t3 * 0.16666667f;
  const float v1 = fmaf(fmaf(fmaf(t, -0.5f, 0.5f), t, 0.5f), t, 0.16666667f);
  const float v2 = fmaf(t3, 0.5f, fmaf(t2, -1.0f, 0.66666667f));
  const float v3 = omt * omt * (omt * 0.16666667f);

  float z = fmaf(xn, 2.80261895f, 4.20392842f);
  z = fminf(fmaxf(z, -40.0f), 40.0f);            // overflow guard (inf*0)
  const float d3 = z - 3.60336723f;              // 3*DLT
  const float R3 = __builtin_amdgcn_exp2f(-(d3 * d3));
  const float G  = __builtin_amdgcn_exp2f(z * 2.40224482f);  // 2*DLT
  const float Gi = __builtin_amdgcn_rcpf(G);
  const float R4 = R3 * (G * 9.11881966e-4f);    // e^-7
  const float R5 = R4 * (G * 1.23409804e-4f);    // e^-9
  const float R6 = R5 * (G * 1.67017007e-5f);    // e^-11
  const float R7 = R6 * (G * 2.26032941e-6f);    // e^-13
  const float R2 = R3 * (Gi * 148.413159f);      // e^5
  const float R1 = R2 * (Gi * 20.0855369f);      // e^3
  const float R0 = R1 * (Gi * 2.71828183f);      // e^1
  const float R[8] = {R0, R1, R2, R3, R4, R5, R6, R7};

  float o[8];
#pragma unroll
  for (int j = 0; j < 8; ++j) {   // compares c==k CSE across j (11 distinct)
    float sp = (c == j + 3) ? v3 : 0.0f;
    sp = (c == j + 2) ? v2 : sp;
    sp = (c == j + 1) ? v1 : sp;
    sp = (c == j)     ? v0 : sp;
    o[j] = sp + R[j];
  }
  unsigned pk[4];
#pragma unroll
  for (int h = 0; h < 4; ++h)
    asm("v_cvt_pk_bf16_f32 %0, %1, %2" : "=v"(pk[h]) : "v"(o[2 * h]), "v"(o[2 * h + 1]));
  const uint4 v4 = {pk[0], pk[1], pk[2], pk[3]};
  *(uint4*)dst = v4;  // ds_write_b128
}

// ---------------- fused pipelined bf16 MFMA GEMM -------------------------
// LDS slot (r, c) holds global chunk c ^ (r & 7)  (XOR bank swizzle)
#define GLL(g, l)                                               \
  __builtin_amdgcn_global_load_lds(                             \
      (const __attribute__((address_space(1))) void*)(g),       \
      (__attribute__((address_space(3))) void*)(l), 16, 0, 0)

__global__ __launch_bounds__(512, 2) void gemm_kernel(
    const short* __restrict__ A0, const short* __restrict__ XN,
    const short* __restrict__ W, float* __restrict__ out) {
  __shared__ short As[2 * 128 * 64];  // 32 KB (double-buffered)
  __shared__ short Bs[2 * 256 * 64];  // 64 KB (double-buffered)
  const int tid = threadIdx.x;
  const int lane = tid & 63, wave = tid >> 6;

  const int f = blockIdx.x;          // 256 blocks: pair 2g,2g+1 shares A m-tile
  const int m0 = (f >> 1) * 128;
  const int n0 = (f & 1) * 256;
  const int wm = wave & 1, wn = wave >> 1;  // per-wave 64x64 output

  const f32x4 zero = {0.0f, 0.0f, 0.0f, 0.0f};
  f32x4 acc[4][4];
#pragma unroll
  for (int i = 0; i < 4; i++)
#pragma unroll
    for (int j = 0; j < 4; j++) acc[i][j] = zero;

  // staging map: thread -> (row r0 = tid>>3 in 0..63, chunk-slot c0 = tid&7)
  const int r0 = tid >> 3;
  const int c0 = tid & 7;
  const int q0 = c0 ^ (r0 & 7);
  const short* gA = A0 + (size_t)(m0 + r0) * D_IN + q0 * 8;
  const short* gB = W + (size_t)(n0 + r0) * KTOT + q0 * 8;
  const unsigned short* gXa =
      (const unsigned short*)XN + (size_t)(m0 + r0) * D_IN + q0;
  const unsigned short* gXb = gXa + (size_t)64 * D_IN;

  short* As0 = As;             short* As1 = As + 128 * 64;
  short* Bs0 = Bs;             short* Bs1 = Bs + 256 * 64;

  const int lr = lane & 15;
  const int q = lane >> 4;
  const int x7 = lr & 7;

  // prologue: stage tile 0 into buffer 0; preload xn for first basis tile
  GLL(gA, As0 + wave * 512);
  GLL(gA + (size_t)64 * D_IN, As0 + 4096 + wave * 512);
#pragma unroll
  for (int rd = 0; rd < 4; rd++)
    GLL(gB + (size_t)(64 * rd) * KTOT, Bs0 + wave * 512 + rd * 4096);
  unsigned short pa = gXa[0];
  unsigned short pb = gXb[0];
  __syncthreads();

  const int NT = KTOT / 64;  // 72
  for (int t = 0; t < NT; ++t) {
    const int pr = t & 1;
    const short* aC = pr ? As1 : As0;
    const short* bC = pr ? Bs1 : Bs0;
    short* aN = pr ? As0 : As1;
    short* bN = pr ? Bs0 : Bs1;

    // fragments of current tile -> registers (frees LDS consumers early)
    short8 af[2][4], bfv[2][4];
#pragma unroll
    for (int kk2 = 0; kk2 < 2; kk2++) {
      const int off = ((kk2 * 4 + q) ^ x7) * 8;
#pragma unroll
      for (int mi = 0; mi < 4; mi++)
        af[kk2][mi] = *(const short8*)&aC[(wm * 64 + mi * 16 + lr) * 64 + off];
#pragma unroll
      for (int nj = 0; nj < 4; nj++)
        bfv[kk2][nj] = *(const short8*)&bC[(wn * 64 + nj * 16 + lr) * 64 + off];
    }

    // stage next tile into the other buffer (overlaps with MFMA below)
    const int ktn = t * 64 + 64;
    if (ktn < KTOT) {
#pragma unroll
      for (int rd = 0; rd < 4; rd++)
        GLL(gB + (size_t)(64 * rd) * KTOT + ktn, bN + wave * 512 + rd * 4096);
      if (ktn < D_IN) {
        GLL(gA + ktn, aN + wave * 512);
        GLL(gA + (size_t)64 * D_IN + ktn, aN + 4096 + wave * 512);
      } else {
        const float xa = h2f(pa), xb = h2f(pb);
        const int dofn = (ktn - D_IN) >> 3;
        pa = gXa[dofn + 8];  // prefetch tile after next (lands in ws, safe)
        pb = gXb[dofn + 8];
        basis_write(xa, (short*)&aN[r0 * 64 + c0 * 8]);
        basis_write(xb, (short*)&aN[(r0 + 64) * 64 + c0 * 8]);
      }
    }

    // MFMA on current tile (independent of staging -> compiler interleaves)
#pragma unroll
    for (int kk2 = 0; kk2 < 2; kk2++)
#pragma unroll
      for (int mi = 0; mi < 4; mi++)
#pragma unroll
        for (int nj = 0; nj < 4; nj++)
          acc[mi][nj] = __builtin_amdgcn_mfma_f32_16x16x32_bf16(
              af[kk2][mi], bfv[kk2][nj], acc[mi][nj], 0, 0, 0);

    __syncthreads();  // next-tile writes visible; current-tile reads drained
  }

  // C/D layout (m89-verified): col = lane&15, row = (lane>>4)*4 + reg
#pragma unroll
  for (int mi = 0; mi < 4; mi++) {
#pragma unroll
    for (int nj = 0; nj < 4; nj++) {
      const int gcol = n0 + wn * 64 + nj * 16 + lr;
#pragma unroll
      for (int r = 0; r < 4; r++) {
        const int grow = m0 + wm * 64 + mi * 16 + q * 4 + r;
        out[(size_t)grow * D_OUT + gcol] = acc[mi][nj][r];
      }
    }
  }
}

extern "C" void kernel_launch(void* const* d_in, const int* in_sizes, int n_in,
                              void* d_out, int out_size, void* d_ws, size_t ws_size,
                              hipStream_t stream) {
  const float* x     = (const float*)d_in[0];
  const float* gamma = (const float*)d_in[1];
  const float* beta  = (const float*)d_in[2];
  const float* bw    = (const float*)d_in[3];
  const float* sw    = (const float*)d_in[4];
  float* out = (float*)d_out;

  short* W  = (short*)d_ws;                          // 512 * 4608 bf16
  short* XN = W + (size_t)D_OUT * KTOT;              // 16384 * 512 fp16
  short* A0 = XN + (size_t)ROWS * D_IN;              // 16384 * 512 bf16

  prep_kernel<<<ROWS / 4 + D_OUT, 256, 0, stream>>>(x, gamma, beta, bw, sw,
                                                    XN, A0, W);
  gemm_kernel<<<256, 512, 0, stream>>>(A0, XN, W, out);
}